// Round 1
// baseline (1714.107 us; speedup 1.0000x reference)
//
#include <hip/hip_runtime.h>

#define NN 100000
#define NE 1600000
#define NG 2000
#define DIM 256
#define NF 4

// ---------------- degree counting ----------------
__global__ void k_count(const int* __restrict__ src, const int* __restrict__ dst,
                        int* __restrict__ outd, int* __restrict__ ind) {
    int i = blockIdx.x * blockDim.x + threadIdx.x;
    int stride = gridDim.x * blockDim.x;
    for (; i < NE; i += stride) {
        atomicAdd(&outd[src[i]], 1);
        atomicAdd(&ind[dst[i]], 1);
    }
}

// ---------------- norms ----------------
__global__ void k_norms(const int* __restrict__ outd, const int* __restrict__ ind,
                        float* __restrict__ onorm, float* __restrict__ inorm) {
    int i = blockIdx.x * blockDim.x + threadIdx.x;
    if (i < NN) {
        int od = outd[i];
        int id = ind[i];
        onorm[i] = od > 0 ? rsqrtf((float)od) : 0.f;
        inorm[i] = id > 0 ? rsqrtf((float)id) : 0.f;
    }
}

// ---------------- exclusive scan of in-degrees (single block, 1024 threads) ----------------
__global__ __launch_bounds__(1024) void k_scan(const int* __restrict__ deg,
                                               int* __restrict__ rowptr,
                                               int* __restrict__ cursor) {
    __shared__ int partial[1024];
    int t = threadIdx.x;
    const int chunk = (NN + 1023) / 1024;
    int begin = t * chunk;
    int end = begin + chunk;
    if (end > NN) end = NN;
    int s = 0;
    for (int i = begin; i < end; ++i) s += deg[i];
    partial[t] = s;
    __syncthreads();
    // Hillis-Steele inclusive scan
    for (int off = 1; off < 1024; off <<= 1) {
        int v = (t >= off) ? partial[t - off] : 0;
        __syncthreads();
        partial[t] += v;
        __syncthreads();
    }
    int run = (t == 0) ? 0 : partial[t - 1];
    for (int i = begin; i < end; ++i) {
        rowptr[i] = run;
        cursor[i] = run;
        run += deg[i];
    }
    if (t == 1023) rowptr[NN] = partial[1023];
}

// ---------------- scatter edges into dst-CSR ----------------
__global__ void k_scatter(const int* __restrict__ src, const int* __restrict__ dst,
                          int* __restrict__ cursor, int* __restrict__ col) {
    int i = blockIdx.x * blockDim.x + threadIdx.x;
    int stride = gridDim.x * blockDim.x;
    for (; i < NE; i += stride) {
        int d = dst[i];
        int p = atomicAdd(&cursor[d], 1);
        col[p] = src[i];
    }
}

// ---------------- embedding sum + out_norm prescale ----------------
__global__ void k_embed(const int* __restrict__ feat, const float* __restrict__ emb,
                        const float* __restrict__ onorm, float* __restrict__ h) {
    int idx = blockIdx.x * blockDim.x + threadIdx.x;  // NN*64 threads
    int node = idx >> 6;
    int g = idx & 63;
    if (node >= NN) return;
    const int4 f = *reinterpret_cast<const int4*>(feat + node * 4);
    const float4* emb4 = reinterpret_cast<const float4*>(emb);
    float4 a = emb4[(long)f.x * 64 + g];
    float4 b = emb4[(long)f.y * 64 + g];
    float4 c = emb4[(long)f.z * 64 + g];
    float4 d = emb4[(long)f.w * 64 + g];
    float sc = onorm[node];
    float4 r;
    r.x = (a.x + b.x + c.x + d.x) * sc;
    r.y = (a.y + b.y + c.y + d.y) * sc;
    r.z = (a.z + b.z + c.z + d.z) * sc;
    r.w = (a.w + b.w + c.w + d.w) * sc;
    reinterpret_cast<float4*>(h)[(long)node * 64 + g] = r;
}

// ---------------- aggregation: one wave per dst node ----------------
// MODE 0: hout = relu(acc * inorm) * onorm   (epilogue feeding next layer)
// MODE 1: pool[gid] += acc * inorm           (final layer + graph pooling)
template <int MODE>
__global__ void k_agg(const int* __restrict__ rowptr, const int* __restrict__ col,
                      const float* __restrict__ hin, const float* __restrict__ inorm,
                      const float* __restrict__ onorm, float* __restrict__ hout,
                      const int* __restrict__ gids, float* __restrict__ pool) {
    int wid = (blockIdx.x * blockDim.x + threadIdx.x) >> 6;
    int lane = threadIdx.x & 63;
    if (wid >= NN) return;
    int e0 = rowptr[wid];
    int e1 = rowptr[wid + 1];
    const float4* hin4 = reinterpret_cast<const float4*>(hin);
    float4 acc = {0.f, 0.f, 0.f, 0.f};
    for (int e = e0; e < e1; ++e) {
        int s = col[e];  // wave-uniform
        float4 v = hin4[(long)s * 64 + lane];
        acc.x += v.x; acc.y += v.y; acc.z += v.z; acc.w += v.w;
    }
    float sc = inorm[wid];
    if (MODE == 0) {
        float on = onorm[wid];
        float4 r;
        r.x = fmaxf(acc.x * sc, 0.f) * on;
        r.y = fmaxf(acc.y * sc, 0.f) * on;
        r.z = fmaxf(acc.z * sc, 0.f) * on;
        r.w = fmaxf(acc.w * sc, 0.f) * on;
        reinterpret_cast<float4*>(hout)[(long)wid * 64 + lane] = r;
    } else {
        int g = gids[wid];
        float* p = pool + (long)g * DIM + lane * 4;
        atomicAdd(p + 0, acc.x * sc);
        atomicAdd(p + 1, acc.y * sc);
        atomicAdd(p + 2, acc.z * sc);
        atomicAdd(p + 3, acc.w * sc);
    }
}

// ---------------- fp32 GEMM: y[NN,256] = x[NN,256] @ W[256,256] ----------------
// block = 256 threads (4 waves); block computes 32 rows x 256 cols.
// wave w handles rows rbase + w*8 .. +8; lane owns cols lane*4..lane*4+3.
__global__ __launch_bounds__(256) void k_gemm(const float* __restrict__ x,
                                              const float* __restrict__ W,
                                              float* __restrict__ y) {
    __shared__ float ws[32][DIM];      // 32 KB : W[k0..k0+32][0..256)
    __shared__ float xs[32][32];       // 4 KB  : x[rbase..+32][k0..k0+32)
    int tid = threadIdx.x;
    int w = tid >> 6;
    int lane = tid & 63;
    int rbase = blockIdx.x * 32;

    float4 acc[8];
#pragma unroll
    for (int r = 0; r < 8; ++r) acc[r] = make_float4(0.f, 0.f, 0.f, 0.f);

    const float4* x4 = reinterpret_cast<const float4*>(x);
    const float4* W4 = reinterpret_cast<const float4*>(W);

    for (int k0 = 0; k0 < DIM; k0 += 32) {
        // stage x tile: 32 rows x 32 k = 256 float4, one per thread
        {
            int rr = tid >> 3;            // 0..31
            int cc = tid & 7;             // 0..7 (float4 within 32 k)
            float4 v = x4[(long)(rbase + rr) * 64 + (k0 >> 2) + cc];
            xs[rr][cc * 4 + 0] = v.x;
            xs[rr][cc * 4 + 1] = v.y;
            xs[rr][cc * 4 + 2] = v.z;
            xs[rr][cc * 4 + 3] = v.w;
        }
        // stage W tile: 32 k x 256 cols = 2048 float4, 8 per thread
#pragma unroll
        for (int i = 0; i < 8; ++i) {
            int idx = tid + i * 256;      // 0..2047
            int kk = idx >> 6;            // 0..31
            int c4 = idx & 63;            // float4 col
            float4 v = W4[(long)(k0 + kk) * 64 + c4];
            ws[kk][c4 * 4 + 0] = v.x;
            ws[kk][c4 * 4 + 1] = v.y;
            ws[kk][c4 * 4 + 2] = v.z;
            ws[kk][c4 * 4 + 3] = v.w;
        }
        __syncthreads();
#pragma unroll 4
        for (int k = 0; k < 32; ++k) {
            float4 wv = *reinterpret_cast<const float4*>(&ws[k][lane * 4]);
#pragma unroll
            for (int r = 0; r < 8; ++r) {
                float xv = xs[w * 8 + r][k];
                acc[r].x += xv * wv.x;
                acc[r].y += xv * wv.y;
                acc[r].z += xv * wv.z;
                acc[r].w += xv * wv.w;
            }
        }
        __syncthreads();
    }

    float4* y4 = reinterpret_cast<float4*>(y);
#pragma unroll
    for (int r = 0; r < 8; ++r) {
        int row = rbase + w * 8 + r;
        y4[(long)row * 64 + lane] = acc[r];
    }
}

extern "C" void kernel_launch(void* const* d_in, const int* in_sizes, int n_in,
                              void* d_out, int out_size, void* d_ws, size_t ws_size,
                              hipStream_t stream) {
    const int* feature = (const int*)d_in[0];
    const int* src = (const int*)d_in[1];
    const int* dst = (const int*)d_in[2];
    const int* gids = (const int*)d_in[3];
    const float* emb = (const float*)d_in[4];
    const float* W1 = (const float*)d_in[5];
    const float* W2 = (const float*)d_in[6];
    float* out = (float*)d_out;

    // workspace carve (all 16B aligned)
    char* p = (char*)d_ws;
    float* hA = (float*)p;              p += (size_t)NN * DIM * 4;
    float* hB = (float*)p;              p += (size_t)NN * DIM * 4;
    float* onorm = (float*)p;           p += (size_t)NN * 4;
    float* inorm = (float*)p;           p += (size_t)NN * 4;
    int* rowptr = (int*)p;              p += (size_t)(NN + 4) * 4;
    int* cursor = (int*)p;              p += (size_t)NN * 4;
    int* colidx = (int*)p;              p += (size_t)NE * 4;
    int* outd = (int*)p;                p += (size_t)NN * 4;
    int* ind = (int*)p;                 p += (size_t)NN * 4;

    // zero degree counts (contiguous outd|ind) and output
    hipMemsetAsync(outd, 0, (size_t)2 * NN * 4, stream);
    hipMemsetAsync(d_out, 0, (size_t)NG * DIM * 4, stream);

    k_count<<<2048, 256, 0, stream>>>(src, dst, outd, ind);
    k_norms<<<(NN + 255) / 256, 256, 0, stream>>>(outd, ind, onorm, inorm);
    k_scan<<<1, 1024, 0, stream>>>(ind, rowptr, cursor);
    k_scatter<<<2048, 256, 0, stream>>>(src, dst, cursor, colidx);

    // h0 = (sum_f emb[feature]) * out_norm
    k_embed<<<(NN * 64 + 255) / 256, 256, 0, stream>>>(feature, emb, onorm, hA);

    const int aggGrid = (NN * 64 + 255) / 256;
    // layer 0 (no W): hB = relu(agg(hA) * inorm) * onorm
    k_agg<0><<<aggGrid, 256, 0, stream>>>(rowptr, colidx, hA, inorm, onorm, hB, gids, out);
    // layer 1: hA = hB @ W1 ; hB = relu(agg(hA) * inorm) * onorm
    k_gemm<<<NN / 32 + (NN % 32 ? 1 : 0), 256, 0, stream>>>(hB, W1, hA);
    k_agg<0><<<aggGrid, 256, 0, stream>>>(rowptr, colidx, hA, inorm, onorm, hB, gids, out);
    // layer 2: hA = hB @ W2 ; pool += agg(hA) * inorm
    k_gemm<<<NN / 32 + (NN % 32 ? 1 : 0), 256, 0, stream>>>(hB, W2, hA);
    k_agg<1><<<aggGrid, 256, 0, stream>>>(rowptr, colidx, hA, inorm, onorm, nullptr, gids, out);
}

// Round 2
// 1434.182 us; speedup vs baseline: 1.1952x; 1.1952x over previous
//
#include <hip/hip_runtime.h>
#include <hip/hip_fp16.h>

#define NN 100000
#define NE 1600000
#define NG 2000
#define DIM 256
#define NF 4

__device__ inline float4 h4_to_f4(uint2 v) {
    __half2 a = *reinterpret_cast<__half2*>(&v.x);
    __half2 b = *reinterpret_cast<__half2*>(&v.y);
    float2 fa = __half22float2(a);
    float2 fb = __half22float2(b);
    return make_float4(fa.x, fa.y, fb.x, fb.y);
}

__device__ inline uint2 f4_to_h4(float4 r) {
    __half2 a = __floats2half2_rn(r.x, r.y);
    __half2 b = __floats2half2_rn(r.z, r.w);
    uint2 o;
    o.x = *reinterpret_cast<uint*>(&a);
    o.y = *reinterpret_cast<uint*>(&b);
    return o;
}

// ---------------- degree counting ----------------
__global__ void k_count(const int* __restrict__ src, const int* __restrict__ dst,
                        int* __restrict__ outd, int* __restrict__ ind) {
    int i = blockIdx.x * blockDim.x + threadIdx.x;
    int stride = gridDim.x * blockDim.x;
    for (; i < NE; i += stride) {
        atomicAdd(&outd[src[i]], 1);
        atomicAdd(&ind[dst[i]], 1);
    }
}

// ---------------- norms ----------------
__global__ void k_norms(const int* __restrict__ outd, const int* __restrict__ ind,
                        float* __restrict__ onorm, float* __restrict__ inorm) {
    int i = blockIdx.x * blockDim.x + threadIdx.x;
    if (i < NN) {
        int od = outd[i];
        int id = ind[i];
        onorm[i] = od > 0 ? rsqrtf((float)od) : 0.f;
        inorm[i] = id > 0 ? rsqrtf((float)id) : 0.f;
    }
}

// ---------------- exclusive scan of in-degrees (single block, 1024 threads) ----------------
__global__ __launch_bounds__(1024) void k_scan(const int* __restrict__ deg,
                                               int* __restrict__ rowptr,
                                               int* __restrict__ cursor) {
    __shared__ int partial[1024];
    int t = threadIdx.x;
    const int chunk = (NN + 1023) / 1024;
    int begin = t * chunk;
    int end = begin + chunk;
    if (end > NN) end = NN;
    int s = 0;
    for (int i = begin; i < end; ++i) s += deg[i];
    partial[t] = s;
    __syncthreads();
    for (int off = 1; off < 1024; off <<= 1) {
        int v = (t >= off) ? partial[t - off] : 0;
        __syncthreads();
        partial[t] += v;
        __syncthreads();
    }
    int run = (t == 0) ? 0 : partial[t - 1];
    for (int i = begin; i < end; ++i) {
        rowptr[i] = run;
        cursor[i] = run;
        run += deg[i];
    }
    if (t == 1023) rowptr[NN] = partial[1023];
}

// ---------------- scatter edges into dst-CSR ----------------
__global__ void k_scatter(const int* __restrict__ src, const int* __restrict__ dst,
                          int* __restrict__ cursor, int* __restrict__ col) {
    int i = blockIdx.x * blockDim.x + threadIdx.x;
    int stride = gridDim.x * blockDim.x;
    for (; i < NE; i += stride) {
        int d = dst[i];
        int p = atomicAdd(&cursor[d], 1);
        col[p] = src[i];
    }
}

// ---------------- embedding sum + out_norm prescale -> fp16 ----------------
__global__ void k_embed(const int* __restrict__ feat, const float* __restrict__ emb,
                        const float* __restrict__ onorm, ushort* __restrict__ h) {
    int idx = blockIdx.x * blockDim.x + threadIdx.x;  // NN*64 threads
    int node = idx >> 6;
    int g = idx & 63;
    if (node >= NN) return;
    const int4 f = *reinterpret_cast<const int4*>(feat + node * 4);
    const float4* emb4 = reinterpret_cast<const float4*>(emb);
    float4 a = emb4[(long)f.x * 64 + g];
    float4 b = emb4[(long)f.y * 64 + g];
    float4 c = emb4[(long)f.z * 64 + g];
    float4 d = emb4[(long)f.w * 64 + g];
    float sc = onorm[node];
    float4 r;
    r.x = (a.x + b.x + c.x + d.x) * sc;
    r.y = (a.y + b.y + c.y + d.y) * sc;
    r.z = (a.z + b.z + c.z + d.z) * sc;
    r.w = (a.w + b.w + c.w + d.w) * sc;
    reinterpret_cast<uint2*>(h)[(long)node * 64 + g] = f4_to_h4(r);
}

// ---------------- aggregation: one wave per dst node (fp16 in, fp32 accum) ----------------
// MODE 0: hout = relu(acc * inorm) * onorm   (fp16, feeds next layer)
// MODE 1: pool[gid] += acc * inorm           (fp32 atomics into d_out)
template <int MODE>
__global__ void k_agg(const int* __restrict__ rowptr, const int* __restrict__ col,
                      const ushort* __restrict__ hin, const float* __restrict__ inorm,
                      const float* __restrict__ onorm, ushort* __restrict__ hout,
                      const int* __restrict__ gids, float* __restrict__ pool) {
    int wid = (blockIdx.x * blockDim.x + threadIdx.x) >> 6;
    int lane = threadIdx.x & 63;
    if (wid >= NN) return;
    int e0 = rowptr[wid];
    int e1 = rowptr[wid + 1];
    const uint2* hin2 = reinterpret_cast<const uint2*>(hin);  // row = 64 uint2
    float4 acc = {0.f, 0.f, 0.f, 0.f};
    int e = e0;
    // unrolled x4: 4 independent gathers in flight
    for (; e + 4 <= e1; e += 4) {
        int s0 = col[e + 0];
        int s1 = col[e + 1];
        int s2 = col[e + 2];
        int s3 = col[e + 3];
        uint2 u0 = hin2[(long)s0 * 64 + lane];
        uint2 u1 = hin2[(long)s1 * 64 + lane];
        uint2 u2 = hin2[(long)s2 * 64 + lane];
        uint2 u3 = hin2[(long)s3 * 64 + lane];
        float4 v0 = h4_to_f4(u0);
        float4 v1 = h4_to_f4(u1);
        float4 v2 = h4_to_f4(u2);
        float4 v3 = h4_to_f4(u3);
        acc.x += (v0.x + v1.x) + (v2.x + v3.x);
        acc.y += (v0.y + v1.y) + (v2.y + v3.y);
        acc.z += (v0.z + v1.z) + (v2.z + v3.z);
        acc.w += (v0.w + v1.w) + (v2.w + v3.w);
    }
    for (; e < e1; ++e) {
        int s = col[e];
        float4 v = h4_to_f4(hin2[(long)s * 64 + lane]);
        acc.x += v.x; acc.y += v.y; acc.z += v.z; acc.w += v.w;
    }
    float sc = inorm[wid];
    if (MODE == 0) {
        float on = onorm[wid];
        float4 r;
        r.x = fmaxf(acc.x * sc, 0.f) * on;
        r.y = fmaxf(acc.y * sc, 0.f) * on;
        r.z = fmaxf(acc.z * sc, 0.f) * on;
        r.w = fmaxf(acc.w * sc, 0.f) * on;
        reinterpret_cast<uint2*>(hout)[(long)wid * 64 + lane] = f4_to_h4(r);
    } else {
        int g = gids[wid];
        float* p = pool + (long)g * DIM + lane * 4;
        atomicAdd(p + 0, acc.x * sc);
        atomicAdd(p + 1, acc.y * sc);
        atomicAdd(p + 2, acc.z * sc);
        atomicAdd(p + 3, acc.w * sc);
    }
}

// ---------------- GEMM: y[NN,256] = x[NN,256] @ W[256,256], fp16 x/y, fp32 W/accum ----
// block = 256 threads (4 waves); block computes 32 rows x 256 cols.
__global__ __launch_bounds__(256) void k_gemm(const ushort* __restrict__ x,
                                              const float* __restrict__ W,
                                              ushort* __restrict__ y) {
    __shared__ float ws[32][DIM];      // 32 KB : W[k0..k0+32][0..256)
    __shared__ float xs[32][32];       // 4 KB  : x[rbase..+32][k0..k0+32)
    int tid = threadIdx.x;
    int w = tid >> 6;
    int lane = tid & 63;
    int rbase = blockIdx.x * 32;

    float4 acc[8];
#pragma unroll
    for (int r = 0; r < 8; ++r) acc[r] = make_float4(0.f, 0.f, 0.f, 0.f);

    const uint2* x2 = reinterpret_cast<const uint2*>(x);   // row = 64 uint2 (4 halves each)
    const float4* W4 = reinterpret_cast<const float4*>(W);

    for (int k0 = 0; k0 < DIM; k0 += 32) {
        // stage x tile: 32 rows x 32 k = 1024 halves; thread t loads 4 halves
        {
            int rr = tid >> 3;            // 0..31
            int cc = tid & 7;             // 0..7 (4 halves each)
            uint2 u = x2[(long)(rbase + rr) * 64 + (k0 >> 2) + cc];
            float4 v = h4_to_f4(u);
            xs[rr][cc * 4 + 0] = v.x;
            xs[rr][cc * 4 + 1] = v.y;
            xs[rr][cc * 4 + 2] = v.z;
            xs[rr][cc * 4 + 3] = v.w;
        }
        // stage W tile: 32 k x 256 cols = 2048 float4, 8 per thread
#pragma unroll
        for (int i = 0; i < 8; ++i) {
            int idx = tid + i * 256;      // 0..2047
            int kk = idx >> 6;            // 0..31
            int c4 = idx & 63;            // float4 col
            float4 v = W4[(long)(k0 + kk) * 64 + c4];
            ws[kk][c4 * 4 + 0] = v.x;
            ws[kk][c4 * 4 + 1] = v.y;
            ws[kk][c4 * 4 + 2] = v.z;
            ws[kk][c4 * 4 + 3] = v.w;
        }
        __syncthreads();
#pragma unroll 4
        for (int k = 0; k < 32; ++k) {
            float4 wv = *reinterpret_cast<const float4*>(&ws[k][lane * 4]);
#pragma unroll
            for (int r = 0; r < 8; ++r) {
                float xv = xs[w * 8 + r][k];
                acc[r].x += xv * wv.x;
                acc[r].y += xv * wv.y;
                acc[r].z += xv * wv.z;
                acc[r].w += xv * wv.w;
            }
        }
        __syncthreads();
    }

    uint2* y2 = reinterpret_cast<uint2*>(y);
#pragma unroll
    for (int r = 0; r < 8; ++r) {
        int row = rbase + w * 8 + r;
        y2[(long)row * 64 + lane] = f4_to_h4(acc[r]);
    }
}

extern "C" void kernel_launch(void* const* d_in, const int* in_sizes, int n_in,
                              void* d_out, int out_size, void* d_ws, size_t ws_size,
                              hipStream_t stream) {
    const int* feature = (const int*)d_in[0];
    const int* src = (const int*)d_in[1];
    const int* dst = (const int*)d_in[2];
    const int* gids = (const int*)d_in[3];
    const float* emb = (const float*)d_in[4];
    const float* W1 = (const float*)d_in[5];
    const float* W2 = (const float*)d_in[6];
    float* out = (float*)d_out;

    // workspace carve (all 16B aligned)
    char* p = (char*)d_ws;
    ushort* hA = (ushort*)p;            p += (size_t)NN * DIM * 2;
    ushort* hB = (ushort*)p;            p += (size_t)NN * DIM * 2;
    float* onorm = (float*)p;           p += (size_t)NN * 4;
    float* inorm = (float*)p;           p += (size_t)NN * 4;
    int* rowptr = (int*)p;              p += (size_t)(NN + 4) * 4;
    int* cursor = (int*)p;              p += (size_t)NN * 4;
    int* colidx = (int*)p;              p += (size_t)NE * 4;
    int* outd = (int*)p;                p += (size_t)NN * 4;
    int* ind = (int*)p;                 p += (size_t)NN * 4;

    hipMemsetAsync(outd, 0, (size_t)2 * NN * 4, stream);
    hipMemsetAsync(d_out, 0, (size_t)NG * DIM * 4, stream);

    k_count<<<2048, 256, 0, stream>>>(src, dst, outd, ind);
    k_norms<<<(NN + 255) / 256, 256, 0, stream>>>(outd, ind, onorm, inorm);
    k_scan<<<1, 1024, 0, stream>>>(ind, rowptr, cursor);
    k_scatter<<<2048, 256, 0, stream>>>(src, dst, cursor, colidx);

    k_embed<<<(NN * 64 + 255) / 256, 256, 0, stream>>>(feature, emb, onorm, hA);

    const int aggGrid = (NN * 64 + 255) / 256;
    // layer 0 (no W): hB = relu(agg(hA) * inorm) * onorm
    k_agg<0><<<aggGrid, 256, 0, stream>>>(rowptr, colidx, hA, inorm, onorm, hB, gids, out);
    // layer 1: hA = hB @ W1 ; hB = relu(agg(hA) * inorm) * onorm
    k_gemm<<<NN / 32 + (NN % 32 ? 1 : 0), 256, 0, stream>>>(hB, W1, hA);
    k_agg<0><<<aggGrid, 256, 0, stream>>>(rowptr, colidx, hA, inorm, onorm, hB, gids, out);
    // layer 2: hA = hB @ W2 ; pool += agg(hA) * inorm
    k_gemm<<<NN / 32 + (NN % 32 ? 1 : 0), 256, 0, stream>>>(hB, W2, hA);
    k_agg<1><<<aggGrid, 256, 0, stream>>>(rowptr, colidx, hA, inorm, onorm, nullptr, gids, out);
}

// Round 3
// 958.334 us; speedup vs baseline: 1.7886x; 1.4965x over previous
//
#include <hip/hip_runtime.h>
#include <hip/hip_fp16.h>

#define NN 100000
#define NE 1600000
#define NG 2000
#define DIM 256
#define NF 4

using half8 = __attribute__((ext_vector_type(8))) _Float16;
using f32x4 = __attribute__((ext_vector_type(4))) float;

__device__ inline float4 h4_to_f4(uint2 v) {
    __half2 a = *reinterpret_cast<__half2*>(&v.x);
    __half2 b = *reinterpret_cast<__half2*>(&v.y);
    float2 fa = __half22float2(a);
    float2 fb = __half22float2(b);
    return make_float4(fa.x, fa.y, fb.x, fb.y);
}

__device__ inline uint2 f4_to_h4(float4 r) {
    __half2 a = __floats2half2_rn(r.x, r.y);
    __half2 b = __floats2half2_rn(r.z, r.w);
    uint2 o;
    o.x = *reinterpret_cast<uint*>(&a);
    o.y = *reinterpret_cast<uint*>(&b);
    return o;
}

// ---------------- degree counting ----------------
__global__ void k_count(const int* __restrict__ src, const int* __restrict__ dst,
                        int* __restrict__ outd, int* __restrict__ ind) {
    int i = blockIdx.x * blockDim.x + threadIdx.x;
    int stride = gridDim.x * blockDim.x;
    for (; i < NE; i += stride) {
        atomicAdd(&outd[src[i]], 1);
        atomicAdd(&ind[dst[i]], 1);
    }
}

// ---------------- norms ----------------
__global__ void k_norms(const int* __restrict__ outd, const int* __restrict__ ind,
                        float* __restrict__ onorm, float* __restrict__ inorm) {
    int i = blockIdx.x * blockDim.x + threadIdx.x;
    if (i < NN) {
        int od = outd[i];
        int id = ind[i];
        onorm[i] = od > 0 ? rsqrtf((float)od) : 0.f;
        inorm[i] = id > 0 ? rsqrtf((float)id) : 0.f;
    }
}

// ---------------- exclusive scan of in-degrees (single block, 1024 threads) ----------------
__global__ __launch_bounds__(1024) void k_scan(const int* __restrict__ deg,
                                               int* __restrict__ rowptr,
                                               int* __restrict__ cursor) {
    __shared__ int partial[1024];
    int t = threadIdx.x;
    const int chunk = (NN + 1023) / 1024;
    int begin = t * chunk;
    int end = begin + chunk;
    if (end > NN) end = NN;
    int s = 0;
    for (int i = begin; i < end; ++i) s += deg[i];
    partial[t] = s;
    __syncthreads();
    for (int off = 1; off < 1024; off <<= 1) {
        int v = (t >= off) ? partial[t - off] : 0;
        __syncthreads();
        partial[t] += v;
        __syncthreads();
    }
    int run = (t == 0) ? 0 : partial[t - 1];
    for (int i = begin; i < end; ++i) {
        rowptr[i] = run;
        cursor[i] = run;
        run += deg[i];
    }
    if (t == 1023) rowptr[NN] = partial[1023];
}

// ---------------- scatter edges into dst-CSR ----------------
__global__ void k_scatter(const int* __restrict__ src, const int* __restrict__ dst,
                          int* __restrict__ cursor, int* __restrict__ col) {
    int i = blockIdx.x * blockDim.x + threadIdx.x;
    int stride = gridDim.x * blockDim.x;
    for (; i < NE; i += stride) {
        int d = dst[i];
        int p = atomicAdd(&cursor[d], 1);
        col[p] = src[i];
    }
}

// ---------------- W (fp32 [k][n]) -> Wt (fp16, transposed [n][k]) ----------------
__global__ void k_wconv(const float* __restrict__ W1, const float* __restrict__ W2,
                        ushort* __restrict__ Wt1, ushort* __restrict__ Wt2) {
    int idx = blockIdx.x * blockDim.x + threadIdx.x;  // 65536
    if (idx >= DIM * DIM) return;
    int k = idx >> 8;
    int n = idx & 255;
    __fp16 a = (__fp16)W1[idx];
    __fp16 b = (__fp16)W2[idx];
    reinterpret_cast<__fp16*>(Wt1)[n * DIM + k] = a;
    reinterpret_cast<__fp16*>(Wt2)[n * DIM + k] = b;
}

// ---------------- embedding sum + out_norm prescale -> fp16 ----------------
__global__ void k_embed(const int* __restrict__ feat, const float* __restrict__ emb,
                        const float* __restrict__ onorm, ushort* __restrict__ h) {
    int idx = blockIdx.x * blockDim.x + threadIdx.x;  // NN*64 threads
    int node = idx >> 6;
    int g = idx & 63;
    if (node >= NN) return;
    const int4 f = *reinterpret_cast<const int4*>(feat + node * 4);
    const float4* emb4 = reinterpret_cast<const float4*>(emb);
    float4 a = emb4[(long)f.x * 64 + g];
    float4 b = emb4[(long)f.y * 64 + g];
    float4 c = emb4[(long)f.z * 64 + g];
    float4 d = emb4[(long)f.w * 64 + g];
    float sc = onorm[node];
    float4 r;
    r.x = (a.x + b.x + c.x + d.x) * sc;
    r.y = (a.y + b.y + c.y + d.y) * sc;
    r.z = (a.z + b.z + c.z + d.z) * sc;
    r.w = (a.w + b.w + c.w + d.w) * sc;
    reinterpret_cast<uint2*>(h)[(long)node * 64 + g] = f4_to_h4(r);
}

// ---------------- aggregation: one wave per dst node (fp16 in, fp32 accum) ----------------
// MODE 0: hout = relu(acc * inorm) * onorm   (fp16, feeds next layer)
// MODE 1: hout = acc * inorm                 (fp16, final layer; pooled separately)
template <int MODE>
__global__ void k_agg(const int* __restrict__ rowptr, const int* __restrict__ col,
                      const ushort* __restrict__ hin, const float* __restrict__ inorm,
                      const float* __restrict__ onorm, ushort* __restrict__ hout) {
    int wid = (blockIdx.x * blockDim.x + threadIdx.x) >> 6;
    int lane = threadIdx.x & 63;
    if (wid >= NN) return;
    int e0 = rowptr[wid];
    int e1 = rowptr[wid + 1];
    const uint2* hin2 = reinterpret_cast<const uint2*>(hin);  // row = 64 uint2
    float4 accA = {0.f, 0.f, 0.f, 0.f};
    float4 accB = {0.f, 0.f, 0.f, 0.f};
    int e = e0;
    // 8 independent gathers in flight
    for (; e + 8 <= e1; e += 8) {
        int s0 = col[e + 0];
        int s1 = col[e + 1];
        int s2 = col[e + 2];
        int s3 = col[e + 3];
        int s4 = col[e + 4];
        int s5 = col[e + 5];
        int s6 = col[e + 6];
        int s7 = col[e + 7];
        uint2 u0 = hin2[(long)s0 * 64 + lane];
        uint2 u1 = hin2[(long)s1 * 64 + lane];
        uint2 u2 = hin2[(long)s2 * 64 + lane];
        uint2 u3 = hin2[(long)s3 * 64 + lane];
        uint2 u4 = hin2[(long)s4 * 64 + lane];
        uint2 u5 = hin2[(long)s5 * 64 + lane];
        uint2 u6 = hin2[(long)s6 * 64 + lane];
        uint2 u7 = hin2[(long)s7 * 64 + lane];
        float4 v0 = h4_to_f4(u0), v1 = h4_to_f4(u1), v2 = h4_to_f4(u2), v3 = h4_to_f4(u3);
        float4 v4 = h4_to_f4(u4), v5 = h4_to_f4(u5), v6 = h4_to_f4(u6), v7 = h4_to_f4(u7);
        accA.x += (v0.x + v1.x) + (v2.x + v3.x);
        accA.y += (v0.y + v1.y) + (v2.y + v3.y);
        accA.z += (v0.z + v1.z) + (v2.z + v3.z);
        accA.w += (v0.w + v1.w) + (v2.w + v3.w);
        accB.x += (v4.x + v5.x) + (v6.x + v7.x);
        accB.y += (v4.y + v5.y) + (v6.y + v7.y);
        accB.z += (v4.z + v5.z) + (v6.z + v7.z);
        accB.w += (v4.w + v5.w) + (v6.w + v7.w);
    }
    for (; e < e1; ++e) {
        int s = col[e];
        float4 v = h4_to_f4(hin2[(long)s * 64 + lane]);
        accA.x += v.x; accA.y += v.y; accA.z += v.z; accA.w += v.w;
    }
    float4 acc;
    acc.x = accA.x + accB.x;
    acc.y = accA.y + accB.y;
    acc.z = accA.z + accB.z;
    acc.w = accA.w + accB.w;
    float sc = inorm[wid];
    float4 r;
    if (MODE == 0) {
        float on = onorm[wid];
        r.x = fmaxf(acc.x * sc, 0.f) * on;
        r.y = fmaxf(acc.y * sc, 0.f) * on;
        r.z = fmaxf(acc.z * sc, 0.f) * on;
        r.w = fmaxf(acc.w * sc, 0.f) * on;
    } else {
        r.x = acc.x * sc;
        r.y = acc.y * sc;
        r.z = acc.z * sc;
        r.w = acc.w * sc;
    }
    reinterpret_cast<uint2*>(hout)[(long)wid * 64 + lane] = f4_to_h4(r);
}

// ---------------- MFMA GEMM: y[NN,256] = x[NN,256] @ W[256,256], fp16 in/out, fp32 accum --
// block = 512 threads (8 waves); block computes 256 rows x 256 cols.
// Wt (transposed W, fp16 [n][k]) staged in 128KB LDS with XOR swizzle.
// Fragment maps (mfma_f32_16x16x32_f16, verified m89/m91 family):
//   A[m][k]: m = l&15, k = (l>>4)*8 + e   (16B contiguous per lane)
//   B[k][n]: n = l&15, k = (l>>4)*8 + e   (16B contiguous from Wt row n)
//   D[m][n]: n = l&15, m = (l>>4)*4 + r
__global__ __launch_bounds__(512, 2) void k_gemm(const ushort* __restrict__ x,
                                                 const ushort* __restrict__ Wt,
                                                 ushort* __restrict__ y) {
    __shared__ char wl[131072];
    int tid = threadIdx.x;
    // stage Wt (256 rows x 512B) into LDS, swizzled: byte ^= ((n&7)<<4)
    const uint4* Wt4 = reinterpret_cast<const uint4*>(Wt);
#pragma unroll
    for (int it = 0; it < 16; ++it) {
        int chunk = it * 512 + tid;      // 0..8191 16B-chunks
        int n = chunk >> 5;              // row 0..255
        int c16 = chunk & 31;
        uint4 v = Wt4[chunk];
        int off = ((n << 9) + (c16 << 4)) ^ ((n & 7) << 4);
        *reinterpret_cast<uint4*>(&wl[off]) = v;
    }
    __syncthreads();

    int w = tid >> 6;
    int l = tid & 63;
    int wrow = blockIdx.x * 256 + w * 32;
    int lrow = l & 15;
    int lk = l >> 4;

    f32x4 acc[2][16];
#pragma unroll
    for (int m = 0; m < 2; ++m)
#pragma unroll
        for (int n = 0; n < 16; ++n) acc[m][n] = {0.f, 0.f, 0.f, 0.f};

    const char* xb = reinterpret_cast<const char*>(x);
    int r0 = wrow + lrow;
    int r1 = r0 + 16;
    r0 = r0 < NN ? r0 : NN - 1;
    r1 = r1 < NN ? r1 : NN - 1;

#pragma unroll
    for (int ks = 0; ks < DIM; ks += 32) {
        long kbyte = (long)(ks + lk * 8) * 2;
        half8 a0 = *reinterpret_cast<const half8*>(xb + (long)r0 * 512 + kbyte);
        half8 a1 = *reinterpret_cast<const half8*>(xb + (long)r1 * 512 + kbyte);
#pragma unroll
        for (int fn = 0; fn < 16; ++fn) {
            int n = fn * 16 + lrow;
            int off = ((n << 9) + (int)kbyte) ^ ((n & 7) << 4);
            half8 b = *reinterpret_cast<const half8*>(&wl[off]);
            acc[0][fn] = __builtin_amdgcn_mfma_f32_16x16x32_f16(a0, b, acc[0][fn], 0, 0, 0);
            acc[1][fn] = __builtin_amdgcn_mfma_f32_16x16x32_f16(a1, b, acc[1][fn], 0, 0, 0);
        }
    }

    __fp16* yh = reinterpret_cast<__fp16*>(y);
#pragma unroll
    for (int m = 0; m < 2; ++m) {
        int rbase = wrow + m * 16 + lk * 4;
#pragma unroll
        for (int fn = 0; fn < 16; ++fn) {
            int colc = fn * 16 + lrow;
#pragma unroll
            for (int r = 0; r < 4; ++r) {
                int row = rbase + r;
                if (row < NN) yh[(long)row * DIM + colc] = (__fp16)acc[m][fn][r];
            }
        }
    }
}

// ---------------- per-graph sum pooling (graph_ids sorted) ----------------
__device__ inline int lbound(const int* __restrict__ a, int n, int v) {
    int lo = 0, hi = n;
    while (lo < hi) {
        int m = (lo + hi) >> 1;
        if (a[m] < v) lo = m + 1; else hi = m;
    }
    return lo;
}

__global__ __launch_bounds__(256) void k_pool(const ushort* __restrict__ h,
                                              const int* __restrict__ gids,
                                              float* __restrict__ out) {
    int g = blockIdx.x;
    int t = threadIdx.x;
    int lo = lbound(gids, NN, g);
    int hi = lbound(gids, NN, g + 1);
    const __fp16* hh = reinterpret_cast<const __fp16*>(h);
    float acc = 0.f;
    for (int nd = lo; nd < hi; ++nd) acc += (float)hh[(long)nd * DIM + t];
    out[(long)g * DIM + t] = acc;
}

extern "C" void kernel_launch(void* const* d_in, const int* in_sizes, int n_in,
                              void* d_out, int out_size, void* d_ws, size_t ws_size,
                              hipStream_t stream) {
    const int* feature = (const int*)d_in[0];
    const int* src = (const int*)d_in[1];
    const int* dst = (const int*)d_in[2];
    const int* gids = (const int*)d_in[3];
    const float* emb = (const float*)d_in[4];
    const float* W1 = (const float*)d_in[5];
    const float* W2 = (const float*)d_in[6];
    float* out = (float*)d_out;

    // workspace carve (all 16B aligned)
    char* p = (char*)d_ws;
    ushort* hA = (ushort*)p;            p += (size_t)NN * DIM * 2;
    ushort* hB = (ushort*)p;            p += (size_t)NN * DIM * 2;
    ushort* Wt1 = (ushort*)p;           p += (size_t)DIM * DIM * 2;
    ushort* Wt2 = (ushort*)p;           p += (size_t)DIM * DIM * 2;
    float* onorm = (float*)p;           p += (size_t)NN * 4;
    float* inorm = (float*)p;           p += (size_t)NN * 4;
    int* rowptr = (int*)p;              p += (size_t)(NN + 4) * 4;
    int* cursor = (int*)p;              p += (size_t)NN * 4;
    int* colidx = (int*)p;              p += (size_t)NE * 4;
    int* outd = (int*)p;                p += (size_t)NN * 4;
    int* ind = (int*)p;                 p += (size_t)NN * 4;

    hipMemsetAsync(outd, 0, (size_t)2 * NN * 4, stream);

    k_count<<<2048, 256, 0, stream>>>(src, dst, outd, ind);
    k_norms<<<(NN + 255) / 256, 256, 0, stream>>>(outd, ind, onorm, inorm);
    k_scan<<<1, 1024, 0, stream>>>(ind, rowptr, cursor);
    k_scatter<<<2048, 256, 0, stream>>>(src, dst, cursor, colidx);
    k_wconv<<<(DIM * DIM + 255) / 256, 256, 0, stream>>>(W1, W2, Wt1, Wt2);

    k_embed<<<(NN * 64 + 255) / 256, 256, 0, stream>>>(feature, emb, onorm, hA);

    const int aggGrid = (NN * 64 + 255) / 256;
    const int gemmGrid = (NN + 255) / 256;
    // layer 0 (no W): hB = relu(agg(hA) * inorm) * onorm
    k_agg<0><<<aggGrid, 256, 0, stream>>>(rowptr, colidx, hA, inorm, onorm, hB);
    // layer 1: hA = hB @ W1 ; hB = relu(agg(hA) * inorm) * onorm
    k_gemm<<<gemmGrid, 512, 0, stream>>>(hB, Wt1, hA);
    k_agg<0><<<aggGrid, 256, 0, stream>>>(rowptr, colidx, hA, inorm, onorm, hB);
    // layer 2: hA = hB @ W2 ; hB = agg(hA) * inorm
    k_gemm<<<gemmGrid, 512, 0, stream>>>(hB, Wt2, hA);
    k_agg<1><<<aggGrid, 256, 0, stream>>>(rowptr, colidx, hA, inorm, onorm, hB);
    // pool per graph
    k_pool<<<NG, 256, 0, stream>>>(hB, gids, out);
}

// Round 4
// 718.520 us; speedup vs baseline: 2.3856x; 1.3338x over previous
//
#include <hip/hip_runtime.h>
#include <hip/hip_fp16.h>

#define NN 100000
#define NE 1600000
#define NG 2000
#define DIM 256
#define NF 4
#define SCAN_B 1024
#define NBLK ((NN + SCAN_B - 1) / SCAN_B)   // 98

using half8 = __attribute__((ext_vector_type(8))) _Float16;
using f32x4 = __attribute__((ext_vector_type(4))) float;

__device__ inline float4 h4_to_f4(uint2 v) {
    __half2 a = *reinterpret_cast<__half2*>(&v.x);
    __half2 b = *reinterpret_cast<__half2*>(&v.y);
    float2 fa = __half22float2(a);
    float2 fb = __half22float2(b);
    return make_float4(fa.x, fa.y, fb.x, fb.y);
}

__device__ inline uint2 f4_to_h4(float4 r) {
    __half2 a = __floats2half2_rn(r.x, r.y);
    __half2 b = __floats2half2_rn(r.z, r.w);
    uint2 o;
    o.x = *reinterpret_cast<uint*>(&a);
    o.y = *reinterpret_cast<uint*>(&b);
    return o;
}

__device__ inline void add8(float4& a0, float4& a1, uint4 u) {
    uint2 lo2; lo2.x = u.x; lo2.y = u.y;
    uint2 hi2; hi2.x = u.z; hi2.y = u.w;
    float4 lo = h4_to_f4(lo2);
    float4 hi = h4_to_f4(hi2);
    a0.x += lo.x; a0.y += lo.y; a0.z += lo.z; a0.w += lo.w;
    a1.x += hi.x; a1.y += hi.y; a1.z += hi.z; a1.w += hi.w;
}

// ---------------- degree counting ----------------
__global__ void k_count(const int* __restrict__ src, const int* __restrict__ dst,
                        int* __restrict__ outd, int* __restrict__ ind) {
    int i = blockIdx.x * blockDim.x + threadIdx.x;
    int stride = gridDim.x * blockDim.x;
    for (; i < NE; i += stride) {
        atomicAdd(&outd[src[i]], 1);
        atomicAdd(&ind[dst[i]], 1);
    }
}

// ---------------- norms ----------------
__global__ void k_norms(const int* __restrict__ outd, const int* __restrict__ ind,
                        float* __restrict__ onorm, float* __restrict__ inorm) {
    int i = blockIdx.x * blockDim.x + threadIdx.x;
    if (i < NN) {
        int od = outd[i];
        int id = ind[i];
        onorm[i] = od > 0 ? rsqrtf((float)od) : 0.f;
        inorm[i] = id > 0 ? rsqrtf((float)id) : 0.f;
    }
}

// ---------------- multi-block exclusive scan of in-degrees ----------------
// phase 1: per-block inclusive scan -> per-element exclusive (local), block totals
__global__ __launch_bounds__(1024) void k_scan1(const int* __restrict__ deg,
                                                int* __restrict__ locex,
                                                int* __restrict__ partials) {
    __shared__ int sm[SCAN_B];
    int t = threadIdx.x;
    int i = blockIdx.x * SCAN_B + t;
    int v = (i < NN) ? deg[i] : 0;
    sm[t] = v;
    __syncthreads();
    for (int off = 1; off < SCAN_B; off <<= 1) {
        int u = (t >= off) ? sm[t - off] : 0;
        __syncthreads();
        sm[t] += u;
        __syncthreads();
    }
    if (i < NN) locex[i] = sm[t] - v;
    if (t == SCAN_B - 1) partials[blockIdx.x] = sm[t];
}

// phase 2: exclusive scan of block totals (NBLK <= 128), writes rowptr[NN]=total
__global__ __launch_bounds__(128) void k_scan2(int* __restrict__ partials,
                                               int* __restrict__ rowptr_last) {
    __shared__ int sm[128];
    int t = threadIdx.x;
    int v = (t < NBLK) ? partials[t] : 0;
    sm[t] = v;
    __syncthreads();
    for (int off = 1; off < 128; off <<= 1) {
        int u = (t >= off) ? sm[t - off] : 0;
        __syncthreads();
        sm[t] += u;
        __syncthreads();
    }
    if (t < NBLK) partials[t] = sm[t] - v;
    if (t == 127) *rowptr_last = sm[127];
}

// phase 3: add block offsets, produce rowptr + cursor
__global__ __launch_bounds__(1024) void k_scan3(const int* __restrict__ locex,
                                                const int* __restrict__ partials,
                                                int* __restrict__ rowptr,
                                                int* __restrict__ cursor) {
    int i = blockIdx.x * SCAN_B + threadIdx.x;
    if (i < NN) {
        int r = locex[i] + partials[blockIdx.x];
        rowptr[i] = r;
        cursor[i] = r;
    }
}

// ---------------- scatter edges into dst-CSR ----------------
__global__ void k_scatter(const int* __restrict__ src, const int* __restrict__ dst,
                          int* __restrict__ cursor, int* __restrict__ col) {
    int i = blockIdx.x * blockDim.x + threadIdx.x;
    int stride = gridDim.x * blockDim.x;
    for (; i < NE; i += stride) {
        int d = dst[i];
        int p = atomicAdd(&cursor[d], 1);
        col[p] = src[i];
    }
}

// ---------------- W (fp32 [k][n]) -> Wt (fp16, transposed [n][k]) ----------------
__global__ void k_wconv(const float* __restrict__ W1, const float* __restrict__ W2,
                        ushort* __restrict__ Wt1, ushort* __restrict__ Wt2) {
    int idx = blockIdx.x * blockDim.x + threadIdx.x;  // 65536
    if (idx >= DIM * DIM) return;
    int k = idx >> 8;
    int n = idx & 255;
    __fp16 a = (__fp16)W1[idx];
    __fp16 b = (__fp16)W2[idx];
    reinterpret_cast<__fp16*>(Wt1)[n * DIM + k] = a;
    reinterpret_cast<__fp16*>(Wt2)[n * DIM + k] = b;
}

// ---------------- embedding sum + out_norm prescale -> fp16 ----------------
__global__ void k_embed(const int* __restrict__ feat, const float* __restrict__ emb,
                        const float* __restrict__ onorm, ushort* __restrict__ h) {
    int idx = blockIdx.x * blockDim.x + threadIdx.x;  // NN*64 threads
    int node = idx >> 6;
    int g = idx & 63;
    if (node >= NN) return;
    const int4 f = *reinterpret_cast<const int4*>(feat + node * 4);
    const float4* emb4 = reinterpret_cast<const float4*>(emb);
    float4 a = emb4[(long)f.x * 64 + g];
    float4 b = emb4[(long)f.y * 64 + g];
    float4 c = emb4[(long)f.z * 64 + g];
    float4 d = emb4[(long)f.w * 64 + g];
    float sc = onorm[node];
    float4 r;
    r.x = (a.x + b.x + c.x + d.x) * sc;
    r.y = (a.y + b.y + c.y + d.y) * sc;
    r.z = (a.z + b.z + c.z + d.z) * sc;
    r.w = (a.w + b.w + c.w + d.w) * sc;
    reinterpret_cast<uint2*>(h)[(long)node * 64 + g] = f4_to_h4(r);
}

// ---------------- aggregation: one wave per dst node ----------------
// 16B/lane loads: lanes 0-31 fetch edge e's row, lanes 32-63 edge e+1's row.
// fp16 in, fp32 accum; __shfl_xor(32) merges the two half-wave partials.
// MODE 0: hout = relu(acc * inorm) * onorm   (fp16, feeds next layer)
// MODE 1: hout = acc * inorm                 (fp16, final layer; pooled separately)
template <int MODE>
__global__ void k_agg(const int* __restrict__ rowptr, const int* __restrict__ col,
                      const ushort* __restrict__ hin, const float* __restrict__ inorm,
                      const float* __restrict__ onorm, ushort* __restrict__ hout) {
    int wid = (blockIdx.x * blockDim.x + threadIdx.x) >> 6;
    int lane = threadIdx.x & 63;
    if (wid >= NN) return;
    int half = lane >> 5;   // 0: even edges, 1: odd edges
    int l32 = lane & 31;    // 16B chunk within the 512B row
    int e0 = rowptr[wid];
    int e1 = rowptr[wid + 1];
    const uint4* hin4 = reinterpret_cast<const uint4*>(hin);  // row = 32 uint4
    float4 aA0 = {0,0,0,0}, aA1 = {0,0,0,0};
    float4 aB0 = {0,0,0,0}, aB1 = {0,0,0,0};
    int e = e0;
    // main: 8 edges per iter, 4 independent 16B gathers per lane in flight
    for (; e + 8 <= e1; e += 8) {
        int s0 = col[e + 0 + half];
        int s1 = col[e + 2 + half];
        int s2 = col[e + 4 + half];
        int s3 = col[e + 6 + half];
        uint4 u0 = hin4[(long)s0 * 32 + l32];
        uint4 u1 = hin4[(long)s1 * 32 + l32];
        uint4 u2 = hin4[(long)s2 * 32 + l32];
        uint4 u3 = hin4[(long)s3 * 32 + l32];
        add8(aA0, aA1, u0);
        add8(aB0, aB1, u1);
        add8(aA0, aA1, u2);
        add8(aB0, aB1, u3);
    }
    // tail: 2 edges per iter (uniform loop bounds; per-half predicate)
    for (; e < e1; e += 2) {
        int idx = e + half;
        if (idx < e1) {
            int s = col[idx];
            uint4 u = hin4[(long)s * 32 + l32];
            add8(aA0, aA1, u);
        }
    }
    float f[8];
    f[0] = aA0.x + aB0.x; f[1] = aA0.y + aB0.y; f[2] = aA0.z + aB0.z; f[3] = aA0.w + aB0.w;
    f[4] = aA1.x + aB1.x; f[5] = aA1.y + aB1.y; f[6] = aA1.z + aB1.z; f[7] = aA1.w + aB1.w;
#pragma unroll
    for (int j = 0; j < 8; ++j) f[j] += __shfl_xor(f[j], 32);

    float sc = inorm[wid];
    float4 r0, r1;
    if (MODE == 0) {
        float on = onorm[wid];
        r0.x = fmaxf(f[0] * sc, 0.f) * on;
        r0.y = fmaxf(f[1] * sc, 0.f) * on;
        r0.z = fmaxf(f[2] * sc, 0.f) * on;
        r0.w = fmaxf(f[3] * sc, 0.f) * on;
        r1.x = fmaxf(f[4] * sc, 0.f) * on;
        r1.y = fmaxf(f[5] * sc, 0.f) * on;
        r1.z = fmaxf(f[6] * sc, 0.f) * on;
        r1.w = fmaxf(f[7] * sc, 0.f) * on;
    } else {
        r0.x = f[0] * sc; r0.y = f[1] * sc; r0.z = f[2] * sc; r0.w = f[3] * sc;
        r1.x = f[4] * sc; r1.y = f[5] * sc; r1.z = f[6] * sc; r1.w = f[7] * sc;
    }
    if (half == 0) {
        uint2 lo = f4_to_h4(r0);
        uint2 hi = f4_to_h4(r1);
        uint4 o; o.x = lo.x; o.y = lo.y; o.z = hi.x; o.w = hi.y;
        reinterpret_cast<uint4*>(hout)[(long)wid * 32 + l32] = o;
    }
}

// ---------------- MFMA GEMM: y[NN,256] = x[NN,256] @ W[256,256], fp16 in/out, fp32 accum --
__global__ __launch_bounds__(512, 2) void k_gemm(const ushort* __restrict__ x,
                                                 const ushort* __restrict__ Wt,
                                                 ushort* __restrict__ y) {
    __shared__ char wl[131072];
    int tid = threadIdx.x;
    const uint4* Wt4 = reinterpret_cast<const uint4*>(Wt);
#pragma unroll
    for (int it = 0; it < 16; ++it) {
        int chunk = it * 512 + tid;      // 0..8191 16B-chunks
        int n = chunk >> 5;              // row 0..255
        int c16 = chunk & 31;
        uint4 v = Wt4[chunk];
        int off = ((n << 9) + (c16 << 4)) ^ ((n & 7) << 4);
        *reinterpret_cast<uint4*>(&wl[off]) = v;
    }
    __syncthreads();

    int w = tid >> 6;
    int l = tid & 63;
    int wrow = blockIdx.x * 256 + w * 32;
    int lrow = l & 15;
    int lk = l >> 4;

    f32x4 acc[2][16];
#pragma unroll
    for (int m = 0; m < 2; ++m)
#pragma unroll
        for (int n = 0; n < 16; ++n) acc[m][n] = {0.f, 0.f, 0.f, 0.f};

    const char* xb = reinterpret_cast<const char*>(x);
    int r0 = wrow + lrow;
    int r1 = r0 + 16;
    r0 = r0 < NN ? r0 : NN - 1;
    r1 = r1 < NN ? r1 : NN - 1;

#pragma unroll
    for (int ks = 0; ks < DIM; ks += 32) {
        long kbyte = (long)(ks + lk * 8) * 2;
        half8 a0 = *reinterpret_cast<const half8*>(xb + (long)r0 * 512 + kbyte);
        half8 a1 = *reinterpret_cast<const half8*>(xb + (long)r1 * 512 + kbyte);
#pragma unroll
        for (int fn = 0; fn < 16; ++fn) {
            int n = fn * 16 + lrow;
            int off = ((n << 9) + (int)kbyte) ^ ((n & 7) << 4);
            half8 b = *reinterpret_cast<const half8*>(&wl[off]);
            acc[0][fn] = __builtin_amdgcn_mfma_f32_16x16x32_f16(a0, b, acc[0][fn], 0, 0, 0);
            acc[1][fn] = __builtin_amdgcn_mfma_f32_16x16x32_f16(a1, b, acc[1][fn], 0, 0, 0);
        }
    }

    __fp16* yh = reinterpret_cast<__fp16*>(y);
#pragma unroll
    for (int m = 0; m < 2; ++m) {
        int rbase = wrow + m * 16 + lk * 4;
#pragma unroll
        for (int fn = 0; fn < 16; ++fn) {
            int colc = fn * 16 + lrow;
#pragma unroll
            for (int r = 0; r < 4; ++r) {
                int row = rbase + r;
                if (row < NN) yh[(long)row * DIM + colc] = (__fp16)acc[m][fn][r];
            }
        }
    }
}

// ---------------- per-graph sum pooling (graph_ids sorted) ----------------
__device__ inline int lbound(const int* __restrict__ a, int n, int v) {
    int lo = 0, hi = n;
    while (lo < hi) {
        int m = (lo + hi) >> 1;
        if (a[m] < v) lo = m + 1; else hi = m;
    }
    return lo;
}

__global__ __launch_bounds__(256) void k_pool(const ushort* __restrict__ h,
                                              const int* __restrict__ gids,
                                              float* __restrict__ out) {
    int g = blockIdx.x;
    int t = threadIdx.x;
    int lo = lbound(gids, NN, g);
    int hi = lbound(gids, NN, g + 1);
    const __fp16* hh = reinterpret_cast<const __fp16*>(h);
    float acc = 0.f;
    for (int nd = lo; nd < hi; ++nd) acc += (float)hh[(long)nd * DIM + t];
    out[(long)g * DIM + t] = acc;
}

extern "C" void kernel_launch(void* const* d_in, const int* in_sizes, int n_in,
                              void* d_out, int out_size, void* d_ws, size_t ws_size,
                              hipStream_t stream) {
    const int* feature = (const int*)d_in[0];
    const int* src = (const int*)d_in[1];
    const int* dst = (const int*)d_in[2];
    const int* gids = (const int*)d_in[3];
    const float* emb = (const float*)d_in[4];
    const float* W1 = (const float*)d_in[5];
    const float* W2 = (const float*)d_in[6];
    float* out = (float*)d_out;

    // workspace carve (all 16B aligned)
    char* p = (char*)d_ws;
    ushort* hA = (ushort*)p;            p += (size_t)NN * DIM * 2;
    ushort* hB = (ushort*)p;            p += (size_t)NN * DIM * 2;
    ushort* Wt1 = (ushort*)p;           p += (size_t)DIM * DIM * 2;
    ushort* Wt2 = (ushort*)p;           p += (size_t)DIM * DIM * 2;
    float* onorm = (float*)p;           p += (size_t)NN * 4;
    float* inorm = (float*)p;           p += (size_t)NN * 4;
    int* rowptr = (int*)p;              p += (size_t)(NN + 4) * 4;
    int* cursor = (int*)p;              p += (size_t)NN * 4;
    int* colidx = (int*)p;              p += (size_t)NE * 4;
    int* outd = (int*)p;                p += (size_t)NN * 4;
    int* ind = (int*)p;                 p += (size_t)NN * 4;
    int* locex = (int*)p;               p += (size_t)NN * 4;
    int* partials = (int*)p;            p += (size_t)128 * 4;

    hipMemsetAsync(outd, 0, (size_t)2 * NN * 4, stream);

    k_count<<<2048, 256, 0, stream>>>(src, dst, outd, ind);
    k_norms<<<(NN + 255) / 256, 256, 0, stream>>>(outd, ind, onorm, inorm);
    k_scan1<<<NBLK, SCAN_B, 0, stream>>>(ind, locex, partials);
    k_scan2<<<1, 128, 0, stream>>>(partials, rowptr + NN);
    k_scan3<<<NBLK, SCAN_B, 0, stream>>>(locex, partials, rowptr, cursor);
    k_scatter<<<2048, 256, 0, stream>>>(src, dst, cursor, colidx);
    k_wconv<<<(DIM * DIM + 255) / 256, 256, 0, stream>>>(W1, W2, Wt1, Wt2);

    k_embed<<<(NN * 64 + 255) / 256, 256, 0, stream>>>(feature, emb, onorm, hA);

    const int aggGrid = (NN * 64 + 255) / 256;
    const int gemmGrid = (NN + 255) / 256;
    // layer 0 (no W): hB = relu(agg(hA) * inorm) * onorm
    k_agg<0><<<aggGrid, 256, 0, stream>>>(rowptr, colidx, hA, inorm, onorm, hB);
    // layer 1: hA = hB @ W1 ; hB = relu(agg(hA) * inorm) * onorm
    k_gemm<<<gemmGrid, 512, 0, stream>>>(hB, Wt1, hA);
    k_agg<0><<<aggGrid, 256, 0, stream>>>(rowptr, colidx, hA, inorm, onorm, hB);
    // layer 2: hA = hB @ W2 ; hB = agg(hA) * inorm
    k_gemm<<<gemmGrid, 512, 0, stream>>>(hB, Wt2, hA);
    k_agg<1><<<aggGrid, 256, 0, stream>>>(rowptr, colidx, hA, inorm, onorm, hB);
    // pool per graph
    k_pool<<<NG, 256, 0, stream>>>(hB, gids, out);
}

// Round 5
// 666.216 us; speedup vs baseline: 2.5729x; 1.0785x over previous
//
#include <hip/hip_runtime.h>
#include <hip/hip_fp16.h>

#define NN 100000
#define NE 1600000
#define NG 2000
#define DIM 256
#define NF 4
#define SCAN_B 1024
#define NBLK ((NN + SCAN_B - 1) / SCAN_B)   // 98

using half8 = __attribute__((ext_vector_type(8))) _Float16;
using f32x4 = __attribute__((ext_vector_type(4))) float;

__device__ inline float4 h4_to_f4(uint2 v) {
    __half2 a = *reinterpret_cast<__half2*>(&v.x);
    __half2 b = *reinterpret_cast<__half2*>(&v.y);
    float2 fa = __half22float2(a);
    float2 fb = __half22float2(b);
    return make_float4(fa.x, fa.y, fb.x, fb.y);
}

__device__ inline uint2 f4_to_h4(float4 r) {
    __half2 a = __floats2half2_rn(r.x, r.y);
    __half2 b = __floats2half2_rn(r.z, r.w);
    uint2 o;
    o.x = *reinterpret_cast<uint*>(&a);
    o.y = *reinterpret_cast<uint*>(&b);
    return o;
}

__device__ inline void add8(float4& a0, float4& a1, uint4 u) {
    uint2 lo2; lo2.x = u.x; lo2.y = u.y;
    uint2 hi2; hi2.x = u.z; hi2.y = u.w;
    float4 lo = h4_to_f4(lo2);
    float4 hi = h4_to_f4(hi2);
    a0.x += lo.x; a0.y += lo.y; a0.z += lo.z; a0.w += lo.w;
    a1.x += hi.x; a1.y += hi.y; a1.z += hi.z; a1.w += hi.w;
}

// ---------------- degree counting + slot capture ----------------
// slot = position of edge within its dst bucket; stored as ushort (max deg << 64K).
__global__ void k_count(const int* __restrict__ src, const int* __restrict__ dst,
                        int* __restrict__ outd, int* __restrict__ ind,
                        ushort* __restrict__ slots) {
    int i = blockIdx.x * blockDim.x + threadIdx.x;
    int stride = gridDim.x * blockDim.x;
    for (; i < NE; i += stride) {
        atomicAdd(&outd[src[i]], 1);
        int s = atomicAdd(&ind[dst[i]], 1);
        slots[i] = (ushort)s;
    }
}

// ---------------- multi-block exclusive scan of in-degrees ----------------
__global__ __launch_bounds__(1024) void k_scan1(const int* __restrict__ deg,
                                                int* __restrict__ locex,
                                                int* __restrict__ partials) {
    __shared__ int sm[SCAN_B];
    int t = threadIdx.x;
    int i = blockIdx.x * SCAN_B + t;
    int v = (i < NN) ? deg[i] : 0;
    sm[t] = v;
    __syncthreads();
    for (int off = 1; off < SCAN_B; off <<= 1) {
        int u = (t >= off) ? sm[t - off] : 0;
        __syncthreads();
        sm[t] += u;
        __syncthreads();
    }
    if (i < NN) locex[i] = sm[t] - v;
    if (t == SCAN_B - 1) partials[blockIdx.x] = sm[t];
}

__global__ __launch_bounds__(128) void k_scan2(int* __restrict__ partials,
                                               int* __restrict__ rowptr_last) {
    __shared__ int sm[128];
    int t = threadIdx.x;
    int v = (t < NBLK) ? partials[t] : 0;
    sm[t] = v;
    __syncthreads();
    for (int off = 1; off < 128; off <<= 1) {
        int u = (t >= off) ? sm[t - off] : 0;
        __syncthreads();
        sm[t] += u;
        __syncthreads();
    }
    if (t < NBLK) partials[t] = sm[t] - v;
    if (t == 127) *rowptr_last = sm[127];
}

// phase 3: rowptr = locex + block offset; also compute norms (fused, per-node pass)
__global__ __launch_bounds__(1024) void k_scan3(const int* __restrict__ locex,
                                                const int* __restrict__ partials,
                                                const int* __restrict__ outd,
                                                const int* __restrict__ ind,
                                                int* __restrict__ rowptr,
                                                float* __restrict__ onorm,
                                                float* __restrict__ inorm) {
    int i = blockIdx.x * SCAN_B + threadIdx.x;
    if (i < NN) {
        rowptr[i] = locex[i] + partials[blockIdx.x];
        int od = outd[i];
        int id = ind[i];
        onorm[i] = od > 0 ? rsqrtf((float)od) : 0.f;
        inorm[i] = id > 0 ? rsqrtf((float)id) : 0.f;
    }
}

// ---------------- scatter edges into dst-CSR (atomic-free) ----------------
__global__ void k_scatter(const int* __restrict__ src, const int* __restrict__ dst,
                          const int* __restrict__ rowptr, const ushort* __restrict__ slots,
                          int* __restrict__ col) {
    int i = blockIdx.x * blockDim.x + threadIdx.x;
    int stride = gridDim.x * blockDim.x;
    for (; i < NE; i += stride) {
        int d = dst[i];
        col[rowptr[d] + (int)slots[i]] = src[i];
    }
}

// ---------------- W (fp32 [k][n]) -> Wt (fp16, transposed [n][k]) ----------------
__global__ void k_wconv(const float* __restrict__ W1, const float* __restrict__ W2,
                        ushort* __restrict__ Wt1, ushort* __restrict__ Wt2) {
    int idx = blockIdx.x * blockDim.x + threadIdx.x;  // 65536
    if (idx >= DIM * DIM) return;
    int k = idx >> 8;
    int n = idx & 255;
    __fp16 a = (__fp16)W1[idx];
    __fp16 b = (__fp16)W2[idx];
    reinterpret_cast<__fp16*>(Wt1)[n * DIM + k] = a;
    reinterpret_cast<__fp16*>(Wt2)[n * DIM + k] = b;
}

// ---------------- embedding sum + out_norm prescale -> fp16 ----------------
__global__ void k_embed(const int* __restrict__ feat, const float* __restrict__ emb,
                        const float* __restrict__ onorm, ushort* __restrict__ h) {
    int idx = blockIdx.x * blockDim.x + threadIdx.x;  // NN*64 threads
    int node = idx >> 6;
    int g = idx & 63;
    if (node >= NN) return;
    const int4 f = *reinterpret_cast<const int4*>(feat + node * 4);
    const float4* emb4 = reinterpret_cast<const float4*>(emb);
    float4 a = emb4[(long)f.x * 64 + g];
    float4 b = emb4[(long)f.y * 64 + g];
    float4 c = emb4[(long)f.z * 64 + g];
    float4 d = emb4[(long)f.w * 64 + g];
    float sc = onorm[node];
    float4 r;
    r.x = (a.x + b.x + c.x + d.x) * sc;
    r.y = (a.y + b.y + c.y + d.y) * sc;
    r.z = (a.z + b.z + c.z + d.z) * sc;
    r.w = (a.w + b.w + c.w + d.w) * sc;
    reinterpret_cast<uint2*>(h)[(long)node * 64 + g] = f4_to_h4(r);
}

// ---------------- aggregation: one wave per dst node ----------------
// 16B/lane loads: lanes 0-31 fetch edge e's row, lanes 32-63 edge e+1's row.
// MODE 0: hout = relu(acc * inorm) * onorm ; MODE 1: hout = acc * inorm
template <int MODE>
__global__ void k_agg(const int* __restrict__ rowptr, const int* __restrict__ col,
                      const ushort* __restrict__ hin, const float* __restrict__ inorm,
                      const float* __restrict__ onorm, ushort* __restrict__ hout) {
    int wid = (blockIdx.x * blockDim.x + threadIdx.x) >> 6;
    int lane = threadIdx.x & 63;
    if (wid >= NN) return;
    int half = lane >> 5;
    int l32 = lane & 31;
    int e0 = rowptr[wid];
    int e1 = rowptr[wid + 1];
    const uint4* hin4 = reinterpret_cast<const uint4*>(hin);
    float4 aA0 = {0,0,0,0}, aA1 = {0,0,0,0};
    float4 aB0 = {0,0,0,0}, aB1 = {0,0,0,0};
    int e = e0;
    for (; e + 8 <= e1; e += 8) {
        int s0 = col[e + 0 + half];
        int s1 = col[e + 2 + half];
        int s2 = col[e + 4 + half];
        int s3 = col[e + 6 + half];
        uint4 u0 = hin4[(long)s0 * 32 + l32];
        uint4 u1 = hin4[(long)s1 * 32 + l32];
        uint4 u2 = hin4[(long)s2 * 32 + l32];
        uint4 u3 = hin4[(long)s3 * 32 + l32];
        add8(aA0, aA1, u0);
        add8(aB0, aB1, u1);
        add8(aA0, aA1, u2);
        add8(aB0, aB1, u3);
    }
    for (; e < e1; e += 2) {
        int idx = e + half;
        if (idx < e1) {
            int s = col[idx];
            uint4 u = hin4[(long)s * 32 + l32];
            add8(aA0, aA1, u);
        }
    }
    float f[8];
    f[0] = aA0.x + aB0.x; f[1] = aA0.y + aB0.y; f[2] = aA0.z + aB0.z; f[3] = aA0.w + aB0.w;
    f[4] = aA1.x + aB1.x; f[5] = aA1.y + aB1.y; f[6] = aA1.z + aB1.z; f[7] = aA1.w + aB1.w;
#pragma unroll
    for (int j = 0; j < 8; ++j) f[j] += __shfl_xor(f[j], 32);

    float sc = inorm[wid];
    float4 r0, r1;
    if (MODE == 0) {
        float on = onorm[wid];
        r0.x = fmaxf(f[0] * sc, 0.f) * on;
        r0.y = fmaxf(f[1] * sc, 0.f) * on;
        r0.z = fmaxf(f[2] * sc, 0.f) * on;
        r0.w = fmaxf(f[3] * sc, 0.f) * on;
        r1.x = fmaxf(f[4] * sc, 0.f) * on;
        r1.y = fmaxf(f[5] * sc, 0.f) * on;
        r1.z = fmaxf(f[6] * sc, 0.f) * on;
        r1.w = fmaxf(f[7] * sc, 0.f) * on;
    } else {
        r0.x = f[0] * sc; r0.y = f[1] * sc; r0.z = f[2] * sc; r0.w = f[3] * sc;
        r1.x = f[4] * sc; r1.y = f[5] * sc; r1.z = f[6] * sc; r1.w = f[7] * sc;
    }
    if (half == 0) {
        uint2 lo = f4_to_h4(r0);
        uint2 hi = f4_to_h4(r1);
        uint4 o; o.x = lo.x; o.y = lo.y; o.z = hi.x; o.w = hi.y;
        reinterpret_cast<uint4*>(hout)[(long)wid * 32 + l32] = o;
    }
}

// ---------------- MFMA GEMM: y[NN,256] = x[NN,256] @ W[256,256] ----------------
// 512 threads (8 waves); wave computes 48 rows (3 m-frags) x 256 cols; block = 384 rows.
// Wt (fp16 [n][k]) staged in 128KB LDS, XOR-swizzled. Each B ds_read feeds 3 MFMAs.
__global__ __launch_bounds__(512, 2) void k_gemm(const ushort* __restrict__ x,
                                                 const ushort* __restrict__ Wt,
                                                 ushort* __restrict__ y) {
    __shared__ char wl[131072];
    int tid = threadIdx.x;
    const uint4* Wt4 = reinterpret_cast<const uint4*>(Wt);
#pragma unroll
    for (int it = 0; it < 16; ++it) {
        int chunk = it * 512 + tid;      // 0..8191 16B-chunks
        int n = chunk >> 5;              // row 0..255
        int c16 = chunk & 31;
        uint4 v = Wt4[chunk];
        int off = ((n << 9) + (c16 << 4)) ^ ((n & 7) << 4);
        *reinterpret_cast<uint4*>(&wl[off]) = v;
    }
    __syncthreads();

    int w = tid >> 6;
    int l = tid & 63;
    int wrow = blockIdx.x * 384 + w * 48;
    int lrow = l & 15;
    int lk = l >> 4;

    f32x4 acc[3][16];
#pragma unroll
    for (int m = 0; m < 3; ++m)
#pragma unroll
        for (int n = 0; n < 16; ++n) acc[m][n] = {0.f, 0.f, 0.f, 0.f};

    const char* xb = reinterpret_cast<const char*>(x);
    int r0 = wrow + lrow;
    int r1 = r0 + 16;
    int r2 = r0 + 32;
    r0 = r0 < NN ? r0 : NN - 1;
    r1 = r1 < NN ? r1 : NN - 1;
    r2 = r2 < NN ? r2 : NN - 1;

#pragma unroll
    for (int ks = 0; ks < DIM; ks += 32) {
        long kbyte = (long)(ks + lk * 8) * 2;
        half8 a0 = *reinterpret_cast<const half8*>(xb + (long)r0 * 512 + kbyte);
        half8 a1 = *reinterpret_cast<const half8*>(xb + (long)r1 * 512 + kbyte);
        half8 a2 = *reinterpret_cast<const half8*>(xb + (long)r2 * 512 + kbyte);
#pragma unroll
        for (int fn = 0; fn < 16; ++fn) {
            int n = fn * 16 + lrow;
            int off = ((n << 9) + (int)kbyte) ^ ((n & 7) << 4);
            half8 b = *reinterpret_cast<const half8*>(&wl[off]);
            acc[0][fn] = __builtin_amdgcn_mfma_f32_16x16x32_f16(a0, b, acc[0][fn], 0, 0, 0);
            acc[1][fn] = __builtin_amdgcn_mfma_f32_16x16x32_f16(a1, b, acc[1][fn], 0, 0, 0);
            acc[2][fn] = __builtin_amdgcn_mfma_f32_16x16x32_f16(a2, b, acc[2][fn], 0, 0, 0);
        }
    }

    __fp16* yh = reinterpret_cast<__fp16*>(y);
#pragma unroll
    for (int m = 0; m < 3; ++m) {
        int rbase = wrow + m * 16 + lk * 4;
#pragma unroll
        for (int fn = 0; fn < 16; ++fn) {
            int colc = fn * 16 + lrow;
#pragma unroll
            for (int r = 0; r < 4; ++r) {
                int row = rbase + r;
                if (row < NN) yh[(long)row * DIM + colc] = (__fp16)acc[m][fn][r];
            }
        }
    }
}

// ---------------- per-graph sum pooling (graph_ids sorted) ----------------
__device__ inline int lbound(const int* __restrict__ a, int n, int v) {
    int lo = 0, hi = n;
    while (lo < hi) {
        int m = (lo + hi) >> 1;
        if (a[m] < v) lo = m + 1; else hi = m;
    }
    return lo;
}

__global__ __launch_bounds__(256) void k_pool(const ushort* __restrict__ h,
                                              const int* __restrict__ gids,
                                              float* __restrict__ out) {
    int g = blockIdx.x;
    int t = threadIdx.x;
    int lo = lbound(gids, NN, g);
    int hi = lbound(gids, NN, g + 1);
    const __fp16* hh = reinterpret_cast<const __fp16*>(h);
    float acc = 0.f;
    for (int nd = lo; nd < hi; ++nd) acc += (float)hh[(long)nd * DIM + t];
    out[(long)g * DIM + t] = acc;
}

extern "C" void kernel_launch(void* const* d_in, const int* in_sizes, int n_in,
                              void* d_out, int out_size, void* d_ws, size_t ws_size,
                              hipStream_t stream) {
    const int* feature = (const int*)d_in[0];
    const int* src = (const int*)d_in[1];
    const int* dst = (const int*)d_in[2];
    const int* gids = (const int*)d_in[3];
    const float* emb = (const float*)d_in[4];
    const float* W1 = (const float*)d_in[5];
    const float* W2 = (const float*)d_in[6];
    float* out = (float*)d_out;

    // workspace carve (all 16B aligned)
    char* p = (char*)d_ws;
    ushort* hA = (ushort*)p;            p += (size_t)NN * DIM * 2;
    ushort* hB = (ushort*)p;            p += (size_t)NN * DIM * 2;
    ushort* Wt1 = (ushort*)p;           p += (size_t)DIM * DIM * 2;
    ushort* Wt2 = (ushort*)p;           p += (size_t)DIM * DIM * 2;
    float* onorm = (float*)p;           p += (size_t)NN * 4;
    float* inorm = (float*)p;           p += (size_t)NN * 4;
    int* rowptr = (int*)p;              p += (size_t)(NN + 4) * 4;
    int* colidx = (int*)p;              p += (size_t)NE * 4;
    int* outd = (int*)p;                p += (size_t)NN * 4;
    int* ind = (int*)p;                 p += (size_t)NN * 4;
    int* locex = (int*)p;               p += (size_t)NN * 4;
    int* partials = (int*)p;            p += (size_t)128 * 4;
    ushort* slots = (ushort*)p;         p += (size_t)NE * 2;

    hipMemsetAsync(outd, 0, (size_t)2 * NN * 4, stream);  // outd | ind contiguous

    k_count<<<2048, 256, 0, stream>>>(src, dst, outd, ind, slots);
    k_scan1<<<NBLK, SCAN_B, 0, stream>>>(ind, locex, partials);
    k_scan2<<<1, 128, 0, stream>>>(partials, rowptr + NN);
    k_scan3<<<NBLK, SCAN_B, 0, stream>>>(locex, partials, outd, ind, rowptr, onorm, inorm);
    k_scatter<<<2048, 256, 0, stream>>>(src, dst, rowptr, slots, colidx);
    k_wconv<<<(DIM * DIM + 255) / 256, 256, 0, stream>>>(W1, W2, Wt1, Wt2);

    k_embed<<<(NN * 64 + 255) / 256, 256, 0, stream>>>(feature, emb, onorm, hA);

    const int aggGrid = (NN * 64 + 255) / 256;
    const int gemmGrid = (NN + 383) / 384;
    // layer 0 (no W): hB = relu(agg(hA) * inorm) * onorm
    k_agg<0><<<aggGrid, 256, 0, stream>>>(rowptr, colidx, hA, inorm, onorm, hB);
    // layer 1: hA = hB @ W1 ; hB = relu(agg(hA) * inorm) * onorm
    k_gemm<<<gemmGrid, 512, 0, stream>>>(hB, Wt1, hA);
    k_agg<0><<<aggGrid, 256, 0, stream>>>(rowptr, colidx, hA, inorm, onorm, hB);
    // layer 2: hA = hB @ W2 ; hB = agg(hA) * inorm
    k_gemm<<<gemmGrid, 512, 0, stream>>>(hB, Wt2, hA);
    k_agg<1><<<aggGrid, 256, 0, stream>>>(rowptr, colidx, hA, inorm, onorm, hB);
    // pool per graph
    k_pool<<<NG, 256, 0, stream>>>(hB, gids, out);
}